// Round 14
// baseline (1678.032 us; speedup 1.0000x reference)
//
#include <hip/hip_runtime.h>
#include <hip/hip_bf16.h>

#define BB 32
#define WW 384
#define LL 512
#define ITERS 16
#define NPB (WW * LL)
#define LROWS 514            // 1 + 512 + 1 halo rows
#define RP (LROWS * 8)       // shorts per octet-plane (4112)

typedef __attribute__((ext_vector_type(8))) short bf16x8;
typedef __attribute__((ext_vector_type(4))) float f32x4;

__device__ __forceinline__ float b2f(short s) {
    unsigned u = ((unsigned)(unsigned short)s) << 16;
    float f;
    __builtin_memcpy(&f, &u, 4);
    return f;
}
__device__ __forceinline__ short f2b(float v) {
    __hip_bfloat16 h = __float2bfloat16(v);
    return *(short*)&h;
}

// ---------------------------------------------------------------- prep
// op_w [384(co)][385(ci)][3] f32 -> Wh [3][52][384][8] bf16.
// Conv runs A-hi x B-hi only (state-lo/weight-lo effects ~1e-3, threshold
// 7.9e-3). State keeps full hi/lo in MEMORY so LN/xl stays fp32-accurate.
__global__ void wsplit_op(const float* __restrict__ w, short* __restrict__ wh) {
    int i = blockIdx.x * 256 + threadIdx.x;
    if (i >= 3 * 52 * 384 * 8) return;
    int e = i & 7, co = (i >> 3) % 384, oct = (i >> 3) / 384 % 52,
        tap = i / (8 * 384 * 52);
    int ci = oct * 8 + e;
    float v = (ci < 385) ? w[(co * 385 + ci) * 3 + tap] : 0.f;
    wh[i] = f2b(v);
}

// src [CO_real][384(ci)][3] f32 -> dst [3][48][COD][8] bf16 (co>=CO_real -> 0)
__global__ void wsplit_h(const float* __restrict__ w, short* __restrict__ wh,
                         int COD, int CO_real) {
    int i = blockIdx.x * 256 + threadIdx.x;
    if (i >= 3 * 48 * COD * 8) return;
    int e = i & 7, co = (i >> 3) % COD, oct = (i >> 3) / COD % 48,
        tap = i / (8 * COD * 48);
    int ci = oct * 8 + e;
    float v = (co < CO_real) ? w[(co * 384 + ci) * 3 + tap] : 0.f;
    wh[i] = f2b(v);
}

// Zero halo rows (all buffers), install x channel (octet 48, elem 0) + zero
// pad octets 48..51 in both state ping-pong buffers.
__global__ void init_rows(const float* __restrict__ x, short* itAh, short* itAl,
                          short* itBh, short* itBl, short* a1A, short* a1B,
                          short* a2A, short* a2B) {
    int row = blockIdx.x % LROWS, b = blockIdx.x / LROWS;
    int tid = threadIdx.x;
    size_t sb = (size_t)b * 52 * RP;
    if (row == 0 || row == LROWS - 1) {
        for (int i = tid; i < 52 * 8; i += 64) {
            size_t o = sb + (size_t)(i >> 3) * RP + row * 8 + (i & 7);
            itAh[o] = 0; itAl[o] = 0; itBh[o] = 0; itBl[o] = 0;
        }
        for (int i = tid; i < 48 * 8; i += 64) {
            size_t o = (size_t)b * 48 * RP + (size_t)(i >> 3) * RP + row * 8 + (i & 7);
            a1A[o] = 0; a1B[o] = 0;
        }
        for (int i = tid; i < 32 * 8; i += 64) {
            size_t o = (size_t)b * 32 * RP + (size_t)(i >> 3) * RP + row * 8 + (i & 7);
            a2A[o] = 0; a2B[o] = 0;
        }
    } else if (tid < 32) {
        int oct = 48 + (tid >> 3), e = tid & 7;
        short h = 0, l = 0;
        if (oct == 48 && e == 0) {
            float xv = x[b * LL + row - 1];
            __hip_bfloat16 xh = __float2bfloat16(xv);
            h = *(short*)&xh;
            l = f2b(xv - __bfloat162float(xh));
        }
        size_t o = sb + (size_t)oct * RP + row * 8 + e;
        itAh[o] = h; itAl[o] = l; itBh[o] = h; itBl[o] = l;
    }
}

__global__ void zero_part(float* part, int n) {
    int i = blockIdx.x * 256 + threadIdx.x;
    if (i < n) part[i] = 0.f;
}

// it0 = relu(conv1d(x, proj_w)) -> octet-planar hi/lo + LN stats.
__global__ __launch_bounds__(256) void proj_relu(const float* __restrict__ x,
                                                 const float* __restrict__ wp,
                                                 short* __restrict__ oh,
                                                 short* __restrict__ ol,
                                                 float* __restrict__ part) {
    int b = blockIdx.x >> 3, sl = blockIdx.x & 7;
    int tid = threadIdx.x;
    __shared__ float ws[WW * 3];
    __shared__ float xs[66];
    for (int i = tid; i < WW * 3; i += 256) ws[i] = wp[i];
    int l0 = sl * 64;
    for (int i = tid; i < 66; i += 256) {
        int l = l0 + i - 1;
        xs[i] = (l >= 0 && l < LL) ? x[b * LL + l] : 0.f;
    }
    __syncthreads();
    size_t sb = (size_t)b * 52 * RP;
    float s = 0.f, sq = 0.f;
    for (int idx = tid; idx < 64 * WW; idx += 256) {
        int lo = idx / WW, co = idx % WW;
        float v = fmaxf(ws[co * 3] * xs[lo] + ws[co * 3 + 1] * xs[lo + 1] +
                            ws[co * 3 + 2] * xs[lo + 2], 0.f);
        size_t o = sb + (size_t)(co >> 3) * RP + (l0 + lo + 1) * 8 + (co & 7);
        __hip_bfloat16 h = __float2bfloat16(v);
        oh[o] = *(short*)&h;
        ol[o] = f2b(v - __bfloat162float(h));
        s += v; sq += v * v;
    }
    #pragma unroll
    for (int off = 32; off > 0; off >>= 1) {
        s += __shfl_down(s, off);
        sq += __shfl_down(sq, off);
    }
    __shared__ float sr[8];
    int w = tid >> 6;
    if ((tid & 63) == 0) { sr[w] = s; sr[4 + w] = sq; }
    __syncthreads();
    if (tid == 0) {
        atomicAdd(&part[b * 2], sr[0] + sr[1] + sr[2] + sr[3]);
        atomicAdd(&part[b * 2 + 1], sr[4] + sr[5] + sr[6] + sr[7]);
    }
}

// ------------------------------------------------- MFMA implicit-GEMM conv
// Direct-global octet-planar loads, no LDS staging, no K-loop barriers.
// 2-deep SOFTWARE PIPELINE (r13's 3-deep cost 148 VGPR -> crossed the 128
// occupancy step, halving resident waves; depth-2 nominal ~138 packs under
// 128 per the allocator behavior seen in r11/r12). B loads sit 310-620
// SIMD-cyc ahead of use (L2 ~200-300 cyc); A is L1-hot from tap overlap.
// Frags are named scalars via macros (arrays/lambdas defeat SROA -> spills).
// Block: 2 waves splitting co; wave tile 64l x 64co (4x4 16x16x32 MFMA).
// bid layout: g=bid&255 (b*8+lt), ct=bid>>8 -> A-sharers on same XCD.
// MODE 0: relu -> bf16 octet-planar out. MODE 1: energy epilogue + LN stats.

#define DECL_SET(S) \
    bf16x8 ah0##S, ah1##S, ah2##S, ah3##S, bh0##S, bh1##S, bh2##S, bh3##S;

#define LOAD_SET(S)                                                        \
    do {                                                                   \
        size_t ao_ = arow + (size_t)kc * (4 * RP) + tap * 8;               \
        size_t bo_ = brow + (size_t)(tap * CHUNKS + kc) * (4 * COD * 8);   \
        ah0##S = *(const bf16x8*)(inh + ao_);                              \
        ah1##S = *(const bf16x8*)(inh + ao_ + 16 * 8);                     \
        ah2##S = *(const bf16x8*)(inh + ao_ + 32 * 8);                     \
        ah3##S = *(const bf16x8*)(inh + ao_ + 48 * 8);                     \
        bh0##S = *(const bf16x8*)(wh + bo_);                               \
        bh1##S = *(const bf16x8*)(wh + bo_ + 16 * 8);                      \
        bh2##S = *(const bf16x8*)(wh + bo_ + 32 * 8);                      \
        bh3##S = *(const bf16x8*)(wh + bo_ + 48 * 8);                      \
        tap++;                                                             \
        if (tap == 3) { tap = 0; kc++; }                                   \
    } while (0)

#define MM(S, MT, NT)                                                      \
    acc[MT][NT] = __builtin_amdgcn_mfma_f32_16x16x32_bf16(                 \
        ah##MT##S, bh##NT##S, acc[MT][NT], 0, 0, 0);

#define MFMA_SET(S)                                                        \
    do {                                                                   \
        MM(S, 0, 0) MM(S, 0, 1) MM(S, 0, 2) MM(S, 0, 3)                    \
        MM(S, 1, 0) MM(S, 1, 1) MM(S, 1, 2) MM(S, 1, 3)                    \
        MM(S, 2, 0) MM(S, 2, 1) MM(S, 2, 2) MM(S, 2, 3)                    \
        MM(S, 3, 0) MM(S, 3, 1) MM(S, 3, 2) MM(S, 3, 3)                    \
    } while (0)

template <int CHUNKS, int IOCT, int OOCT, int COD, int MODE>
__device__ __forceinline__ void conv_body(
    int bid, const short* __restrict__ inh, const short* __restrict__ inl,
    const short* __restrict__ wh, const float* __restrict__ part_in,
    float* __restrict__ part_out, short* __restrict__ outh,
    short* __restrict__ outl) {
    int g = bid & 255;
    int ct = bid >> 8;
    int b = g >> 3, lt = g & 7;
    int l0 = lt * 64;
    int tid = threadIdx.x;
    int lane = tid & 63;
    int wn = __builtin_amdgcn_readfirstlane(tid >> 6);
    int lane15 = lane & 15, q = lane >> 4;
    int co0 = ct * 128 + wn * 64;
    const size_t ibase = (size_t)b * IOCT * RP;

    f32x4 acc[4][4];
    #pragma unroll
    for (int i = 0; i < 4; i++)
        #pragma unroll
        for (int j = 0; j < 4; j++) acc[i][j] = (f32x4){0.f, 0.f, 0.f, 0.f};

    const size_t arow = ibase + (size_t)q * RP + (l0 + lane15) * 8;
    const size_t brow = ((size_t)q * COD + co0 + lane15) * 8;

    constexpr int NIT = CHUNKS * 3;  // 39 (op) or 36 (h1/h2)
    int kc = 0, tap = 0;

    DECL_SET(A)
    DECL_SET(B)
    LOAD_SET(A);
    if (NIT & 1) {
        int it = 0;
        #pragma unroll 1
        for (; it < NIT / 2; it++) {
            LOAD_SET(B);
            MFMA_SET(A);
            LOAD_SET(A);
            MFMA_SET(B);
        }
        MFMA_SET(A);
    } else {
        int it = 0;
        #pragma unroll 1
        for (; it < NIT / 2 - 1; it++) {
            LOAD_SET(B);
            MFMA_SET(A);
            LOAD_SET(A);
            MFMA_SET(B);
        }
        LOAD_SET(B);
        MFMA_SET(A);
        MFMA_SET(B);
    }

    const size_t obase = (size_t)b * OOCT * RP;
    if (MODE == 1) {
        float s_in = part_in[b * 2], sq_in = part_in[b * 2 + 1];
        float mu = s_in / (float)NPB;
        float var = sq_in / (float)NPB - mu * mu;
        float rs = rsqrtf(var + 1e-5f);
        float s = 0.f, sq = 0.f;
        #pragma unroll
        for (int mt = 0; mt < 4; mt++)
            #pragma unroll
            for (int nt = 0; nt < 4; nt++)
                #pragma unroll
                for (int r = 0; r < 4; r++) {
                    int m = mt * 16 + q * 4 + r;
                    int n = co0 + nt * 16 + lane15;
                    size_t idx = ibase + (size_t)(n >> 3) * RP +
                                 (l0 + m + 1) * 8 + (n & 7);
                    float itv = b2f(inh[idx]) + b2f(inl[idx]);
                    float xl = (itv - mu) * rs;
                    float nv = xl - 0.1f * acc[mt][nt][r] - 0.2f * fmaxf(xl, 0.f);
                    s += nv;
                    sq += nv * nv;
                    __hip_bfloat16 h = __float2bfloat16(nv);
                    outh[idx] = *(short*)&h;
                    outl[idx] = f2b(nv - __bfloat162float(h));
                }
        #pragma unroll
        for (int off = 32; off > 0; off >>= 1) {
            s += __shfl_down(s, off);
            sq += __shfl_down(sq, off);
        }
        __shared__ float sr[4];
        int w = tid >> 6;
        if (lane == 0) { sr[w] = s; sr[2 + w] = sq; }
        __syncthreads();
        if (tid == 0) {
            atomicAdd(&part_out[b * 2], sr[0] + sr[1]);
            atomicAdd(&part_out[b * 2 + 1], sr[2] + sr[3]);
        }
    } else {
        #pragma unroll
        for (int mt = 0; mt < 4; mt++)
            #pragma unroll
            for (int nt = 0; nt < 4; nt++)
                #pragma unroll
                for (int r = 0; r < 4; r++) {
                    int m = mt * 16 + q * 4 + r;
                    int n = co0 + nt * 16 + lane15;
                    size_t idx = obase + (size_t)(n >> 3) * RP +
                                 (l0 + m + 1) * 8 + (n & 7);
                    outh[idx] = f2b(fmaxf(acc[mt][nt][r], 0.f));
                }
    }
}

// Final 192->2 conv body from a2 [32][32oct][514][8] bf16 octet-planar.
__device__ __forceinline__ void h3_body(int bid, const short* __restrict__ a2,
                                        const float* __restrict__ w3,
                                        float* __restrict__ out, int t) {
    __shared__ float ws3[2 * 192 * 3];
    int tid = threadIdx.x;
    for (int i = tid; i < 2 * 192 * 3; i += 128) ws3[i] = w3[i];
    __syncthreads();
    int b = bid >> 3, sl = bid & 7;
    int l = sl * 64 + (tid >> 1);
    int ch = tid & 1;
    const short* ab = a2 + (size_t)b * 32 * RP;
    const float* wc = ws3 + ch * 576;
    float a = 0.f;
    #pragma unroll 4
    for (int oct = 0; oct < 24; oct++) {
        const short* p = ab + (size_t)oct * RP + l * 8;  // row l = seq l-1
        bf16x8 v0 = *(const bf16x8*)p;
        bf16x8 v1 = *(const bf16x8*)(p + 8);
        bf16x8 v2 = *(const bf16x8*)(p + 16);
        #pragma unroll
        for (int j = 0; j < 8; j++) {
            const float* wp = wc + (oct * 8 + j) * 3;
            a += wp[0] * b2f(v0[j]) + wp[1] * b2f(v1[j]) + wp[2] * b2f(v2[j]);
        }
    }
    out[(((size_t)b * ITERS + t) * 2 + ch) * LL + l] = a;
}

// F(t): op(t) || h1(t-1) || h2(t-2) || h3(t-3), one launch per pipeline step.
// All branch reads target buffers written in EARLIER launches (a1/a2
// ping-pong parities break same-launch hazards) -> no intra-launch ordering.
__global__ __launch_bounds__(128) void fusedF(
    const short* __restrict__ ch, const short* __restrict__ cl,
    short* __restrict__ nh, short* __restrict__ nl,
    const short* __restrict__ wOph, const short* __restrict__ wH1,
    const short* __restrict__ wH2, const float* __restrict__ w3,
    const float* __restrict__ part_in, float* __restrict__ part_out,
    short* __restrict__ a1w, const short* __restrict__ a1r,
    short* __restrict__ a2w, const short* __restrict__ a2r,
    float* __restrict__ out, int t3, int opB, int h1B, int h2B) {
    int bid = blockIdx.x;
    if (bid < opB) {
        conv_body<13, 52, 52, 384, 1>(bid, ch, cl, wOph, part_in, part_out,
                                      nh, nl);
    } else if (bid < opB + h1B) {
        conv_body<12, 52, 48, 384, 0>(bid - opB, ch, nullptr, wH1, nullptr,
                                      nullptr, a1w, nullptr);
    } else if (bid < opB + h1B + h2B) {
        conv_body<12, 48, 32, 256, 0>(bid - opB - h1B, a1r, nullptr, wH2,
                                      nullptr, nullptr, a2w, nullptr);
    } else {
        h3_body(bid - opB - h1B - h2B, a2r, w3, out, t3);
    }
}

extern "C" void kernel_launch(void* const* d_in, const int* in_sizes, int n_in,
                              void* d_out, int out_size, void* d_ws, size_t ws_size,
                              hipStream_t stream) {
    const float* x = (const float*)d_in[0];
    const float* proj_w = (const float*)d_in[2];
    const float* op_w = (const float*)d_in[3];
    const float* h1_w = (const float*)d_in[4];
    const float* h2_w = (const float*)d_in[5];
    const float* h3_w = (const float*)d_in[6];
    float* out = (float*)d_out;

    char* base = (char*)d_ws;
    size_t off = 0;
    auto alloc = [&](size_t bytes) {
        char* p = base + off;
        off += (bytes + 255) & ~(size_t)255;
        return p;
    };
    const size_t ITB = (size_t)BB * 52 * RP * 2;  // state buffer bytes
    short* itAh = (short*)alloc(ITB);
    short* itAl = (short*)alloc(ITB);
    short* itBh = (short*)alloc(ITB);
    short* itBl = (short*)alloc(ITB);
    short* a1A = (short*)alloc((size_t)BB * 48 * RP * 2);
    short* a1B = (short*)alloc((size_t)BB * 48 * RP * 2);
    short* a2A = (short*)alloc((size_t)BB * 32 * RP * 2);
    short* a2B = (short*)alloc((size_t)BB * 32 * RP * 2);
    short* wOph = (short*)alloc((size_t)3 * 52 * 384 * 8 * 2);
    short* wH1 = (short*)alloc((size_t)3 * 48 * 384 * 8 * 2);
    short* wH2 = (short*)alloc((size_t)3 * 48 * 256 * 8 * 2);
    float* part = (float*)alloc((size_t)(ITERS + 1) * 64 * 4);
    if (off > ws_size) return;

    wsplit_op<<<(3 * 52 * 384 * 8 + 255) / 256, 256, 0, stream>>>(op_w, wOph);
    wsplit_h<<<(3 * 48 * 384 * 8 + 255) / 256, 256, 0, stream>>>(h1_w, wH1, 384, 384);
    wsplit_h<<<(3 * 48 * 256 * 8 + 255) / 256, 256, 0, stream>>>(h2_w, wH2, 256, 192);
    init_rows<<<BB * LROWS, 64, 0, stream>>>(x, itAh, itAl, itBh, itBl, a1A,
                                             a1B, a2A, a2B);
    zero_part<<<5, 256, 0, stream>>>(part, (ITERS + 1) * 64);
    proj_relu<<<BB * 8, 256, 0, stream>>>(x, proj_w, itAh, itAl, part);

    short* a1buf[2] = {a1A, a1B};
    short* a2buf[2] = {a2A, a2B};
    short *ch = itAh, *cl = itAl, *nh = itBh, *nl = itBl;
    // Pipeline steps t=0..18: op(t<=15), h1(t-1), h2(t-2), h3(t-3).
    for (int t = 0; t <= ITERS + 2; t++) {
        int opB = (t < ITERS) ? 768 : 0;
        int h1B = (t >= 1 && t <= ITERS) ? 768 : 0;
        int h2B = (t >= 2 && t <= ITERS + 1) ? 512 : 0;
        int h3B = (t >= 3) ? 256 : 0;
        int tp = (t < ITERS) ? t : 0;  // part slot (unused when opB==0)
        fusedF<<<opB + h1B + h2B + h3B, 128, 0, stream>>>(
            ch, cl, nh, nl, wOph, wH1, wH2, h3_w, part + tp * 64,
            part + (tp + 1) * 64, a1buf[(t - 1) & 1], a1buf[(t - 2) & 1],
            a2buf[(t - 2) & 1], a2buf[(t - 3) & 1], out, t - 3, opB, h1B, h2B);
        if (t < ITERS) {
            short* th = ch; ch = nh; nh = th;
            short* tl = cl; cl = nl; nl = tl;
        }
    }
}

// Round 15
// 1591.020 us; speedup vs baseline: 1.0547x; 1.0547x over previous
//
#include <hip/hip_runtime.h>
#include <hip/hip_bf16.h>

#define BB 32
#define WW 384
#define LL 512
#define ITERS 16
#define NPB (WW * LL)
#define LROWS 514            // 1 + 512 + 1 halo rows
#define RP (LROWS * 8)       // shorts per octet-plane (4112)

typedef __attribute__((ext_vector_type(8))) short bf16x8;
typedef __attribute__((ext_vector_type(4))) float f32x4;

__device__ __forceinline__ float b2f(short s) {
    unsigned u = ((unsigned)(unsigned short)s) << 16;
    float f;
    __builtin_memcpy(&f, &u, 4);
    return f;
}
__device__ __forceinline__ short f2b(float v) {
    __hip_bfloat16 h = __float2bfloat16(v);
    return *(short*)&h;
}

// ---------------------------------------------------------------- prep
// op_w [384(co)][385(ci)][3] f32 -> Wh [3][52][384][8] bf16.
// Conv runs A-hi x B-hi only (state-lo/weight-lo effects ~1e-3, threshold
// 7.9e-3). State keeps full hi/lo in MEMORY so LN/xl stays fp32-accurate.
__global__ void wsplit_op(const float* __restrict__ w, short* __restrict__ wh) {
    int i = blockIdx.x * 256 + threadIdx.x;
    if (i >= 3 * 52 * 384 * 8) return;
    int e = i & 7, co = (i >> 3) % 384, oct = (i >> 3) / 384 % 52,
        tap = i / (8 * 384 * 52);
    int ci = oct * 8 + e;
    float v = (ci < 385) ? w[(co * 385 + ci) * 3 + tap] : 0.f;
    wh[i] = f2b(v);
}

// src [CO_real][384(ci)][3] f32 -> dst [3][48][COD][8] bf16 (co>=CO_real -> 0)
__global__ void wsplit_h(const float* __restrict__ w, short* __restrict__ wh,
                         int COD, int CO_real) {
    int i = blockIdx.x * 256 + threadIdx.x;
    if (i >= 3 * 48 * COD * 8) return;
    int e = i & 7, co = (i >> 3) % COD, oct = (i >> 3) / COD % 48,
        tap = i / (8 * COD * 48);
    int ci = oct * 8 + e;
    float v = (co < CO_real) ? w[(co * 384 + ci) * 3 + tap] : 0.f;
    wh[i] = f2b(v);
}

// Zero halo rows (all buffers), install x channel (octet 48, elem 0) + zero
// pad octets 48..51 in both state ping-pong buffers.
__global__ void init_rows(const float* __restrict__ x, short* itAh, short* itAl,
                          short* itBh, short* itBl, short* a1A, short* a1B,
                          short* a2A, short* a2B) {
    int row = blockIdx.x % LROWS, b = blockIdx.x / LROWS;
    int tid = threadIdx.x;
    size_t sb = (size_t)b * 52 * RP;
    if (row == 0 || row == LROWS - 1) {
        for (int i = tid; i < 52 * 8; i += 64) {
            size_t o = sb + (size_t)(i >> 3) * RP + row * 8 + (i & 7);
            itAh[o] = 0; itAl[o] = 0; itBh[o] = 0; itBl[o] = 0;
        }
        for (int i = tid; i < 48 * 8; i += 64) {
            size_t o = (size_t)b * 48 * RP + (size_t)(i >> 3) * RP + row * 8 + (i & 7);
            a1A[o] = 0; a1B[o] = 0;
        }
        for (int i = tid; i < 32 * 8; i += 64) {
            size_t o = (size_t)b * 32 * RP + (size_t)(i >> 3) * RP + row * 8 + (i & 7);
            a2A[o] = 0; a2B[o] = 0;
        }
    } else if (tid < 32) {
        int oct = 48 + (tid >> 3), e = tid & 7;
        short h = 0, l = 0;
        if (oct == 48 && e == 0) {
            float xv = x[b * LL + row - 1];
            __hip_bfloat16 xh = __float2bfloat16(xv);
            h = *(short*)&xh;
            l = f2b(xv - __bfloat162float(xh));
        }
        size_t o = sb + (size_t)oct * RP + row * 8 + e;
        itAh[o] = h; itAl[o] = l; itBh[o] = h; itBl[o] = l;
    }
}

__global__ void zero_part(float* part, int n) {
    int i = blockIdx.x * 256 + threadIdx.x;
    if (i < n) part[i] = 0.f;
}

// it0 = relu(conv1d(x, proj_w)) -> octet-planar hi/lo + LN stats.
__global__ __launch_bounds__(256) void proj_relu(const float* __restrict__ x,
                                                 const float* __restrict__ wp,
                                                 short* __restrict__ oh,
                                                 short* __restrict__ ol,
                                                 float* __restrict__ part) {
    int b = blockIdx.x >> 3, sl = blockIdx.x & 7;
    int tid = threadIdx.x;
    __shared__ float ws[WW * 3];
    __shared__ float xs[66];
    for (int i = tid; i < WW * 3; i += 256) ws[i] = wp[i];
    int l0 = sl * 64;
    for (int i = tid; i < 66; i += 256) {
        int l = l0 + i - 1;
        xs[i] = (l >= 0 && l < LL) ? x[b * LL + l] : 0.f;
    }
    __syncthreads();
    size_t sb = (size_t)b * 52 * RP;
    float s = 0.f, sq = 0.f;
    for (int idx = tid; idx < 64 * WW; idx += 256) {
        int lo = idx / WW, co = idx % WW;
        float v = fmaxf(ws[co * 3] * xs[lo] + ws[co * 3 + 1] * xs[lo + 1] +
                            ws[co * 3 + 2] * xs[lo + 2], 0.f);
        size_t o = sb + (size_t)(co >> 3) * RP + (l0 + lo + 1) * 8 + (co & 7);
        __hip_bfloat16 h = __float2bfloat16(v);
        oh[o] = *(short*)&h;
        ol[o] = f2b(v - __bfloat162float(h));
        s += v; sq += v * v;
    }
    #pragma unroll
    for (int off = 32; off > 0; off >>= 1) {
        s += __shfl_down(s, off);
        sq += __shfl_down(sq, off);
    }
    __shared__ float sr[8];
    int w = tid >> 6;
    if ((tid & 63) == 0) { sr[w] = s; sr[4 + w] = sq; }
    __syncthreads();
    if (tid == 0) {
        atomicAdd(&part[b * 2], sr[0] + sr[1] + sr[2] + sr[3]);
        atomicAdd(&part[b * 2 + 1], sr[4] + sr[5] + sr[6] + sr[7]);
    }
}

// ------------------------------------------------- MFMA implicit-GEMM conv
// Direct-global octet-planar loads, no LDS staging, no K-loop barriers.
// 3-deep SOFTWARE PIPELINE (at 3-4 waves/SIMD, depth-3 beats depth-2:
// r14's depth-2 regressed with identical occupancy class). Frags are named
// scalars via macros (arrays/lambdas defeat SROA -> scratch spills, r7/r8).
// __launch_bounds__(128, 4) pins VGPR <= 128 (r13's 148 capped residency at
// 3 waves/SIMD; the ~20 surplus regs are address temps the allocator can
// rematerialize). Tripwire: WRITE_SIZE > 100 MB = hot-loop spill.
// Block: 2 waves splitting co; wave tile 64l x 64co (4x4 16x16x32 MFMA).
// bid layout: g=bid&255 (b*8+lt), ct=bid>>8 -> A-sharers on same XCD.
// MODE 0: relu -> bf16 octet-planar out. MODE 1: energy epilogue + LN stats.

#define DECL_SET(S) \
    bf16x8 ah0##S, ah1##S, ah2##S, ah3##S, bh0##S, bh1##S, bh2##S, bh3##S;

#define LOAD_SET(S)                                                        \
    do {                                                                   \
        size_t ao_ = arow + (size_t)kc * (4 * RP) + tap * 8;               \
        size_t bo_ = brow + (size_t)(tap * CHUNKS + kc) * (4 * COD * 8);   \
        ah0##S = *(const bf16x8*)(inh + ao_);                              \
        ah1##S = *(const bf16x8*)(inh + ao_ + 16 * 8);                     \
        ah2##S = *(const bf16x8*)(inh + ao_ + 32 * 8);                     \
        ah3##S = *(const bf16x8*)(inh + ao_ + 48 * 8);                     \
        bh0##S = *(const bf16x8*)(wh + bo_);                               \
        bh1##S = *(const bf16x8*)(wh + bo_ + 16 * 8);                      \
        bh2##S = *(const bf16x8*)(wh + bo_ + 32 * 8);                      \
        bh3##S = *(const bf16x8*)(wh + bo_ + 48 * 8);                      \
        tap++;                                                             \
        if (tap == 3) { tap = 0; kc++; }                                   \
    } while (0)

#define MM(S, MT, NT)                                                      \
    acc[MT][NT] = __builtin_amdgcn_mfma_f32_16x16x32_bf16(                 \
        ah##MT##S, bh##NT##S, acc[MT][NT], 0, 0, 0);

#define MFMA_SET(S)                                                        \
    do {                                                                   \
        MM(S, 0, 0) MM(S, 0, 1) MM(S, 0, 2) MM(S, 0, 3)                    \
        MM(S, 1, 0) MM(S, 1, 1) MM(S, 1, 2) MM(S, 1, 3)                    \
        MM(S, 2, 0) MM(S, 2, 1) MM(S, 2, 2) MM(S, 2, 3)                    \
        MM(S, 3, 0) MM(S, 3, 1) MM(S, 3, 2) MM(S, 3, 3)                    \
    } while (0)

template <int CHUNKS, int IOCT, int OOCT, int COD, int MODE>
__device__ __forceinline__ void conv_body(
    int bid, const short* __restrict__ inh, const short* __restrict__ inl,
    const short* __restrict__ wh, const float* __restrict__ part_in,
    float* __restrict__ part_out, short* __restrict__ outh,
    short* __restrict__ outl) {
    int g = bid & 255;
    int ct = bid >> 8;
    int b = g >> 3, lt = g & 7;
    int l0 = lt * 64;
    int tid = threadIdx.x;
    int lane = tid & 63;
    int wn = __builtin_amdgcn_readfirstlane(tid >> 6);
    int lane15 = lane & 15, q = lane >> 4;
    int co0 = ct * 128 + wn * 64;
    const size_t ibase = (size_t)b * IOCT * RP;

    f32x4 acc[4][4];
    #pragma unroll
    for (int i = 0; i < 4; i++)
        #pragma unroll
        for (int j = 0; j < 4; j++) acc[i][j] = (f32x4){0.f, 0.f, 0.f, 0.f};

    const size_t arow = ibase + (size_t)q * RP + (l0 + lane15) * 8;
    const size_t brow = ((size_t)q * COD + co0 + lane15) * 8;

    constexpr int NIT = CHUNKS * 3;  // 39 or 36 — both divisible by 3
    static_assert(NIT % 3 == 0, "driver assumes NIT % 3 == 0");
    int kc = 0, tap = 0;

    DECL_SET(A)
    DECL_SET(B)
    DECL_SET(C)
    LOAD_SET(A);
    LOAD_SET(B);
    int it = 0;
    #pragma unroll 1
    for (; it + 5 < NIT; it += 3) {
        LOAD_SET(C);
        MFMA_SET(A);
        LOAD_SET(A);
        MFMA_SET(B);
        LOAD_SET(B);
        MFMA_SET(C);
    }
    LOAD_SET(C);
    MFMA_SET(A);
    MFMA_SET(B);
    MFMA_SET(C);

    const size_t obase = (size_t)b * OOCT * RP;
    if (MODE == 1) {
        float s_in = part_in[b * 2], sq_in = part_in[b * 2 + 1];
        float mu = s_in / (float)NPB;
        float var = sq_in / (float)NPB - mu * mu;
        float rs = rsqrtf(var + 1e-5f);
        float s = 0.f, sq = 0.f;
        #pragma unroll
        for (int mt = 0; mt < 4; mt++)
            #pragma unroll
            for (int nt = 0; nt < 4; nt++)
                #pragma unroll
                for (int r = 0; r < 4; r++) {
                    int m = mt * 16 + q * 4 + r;
                    int n = co0 + nt * 16 + lane15;
                    size_t idx = ibase + (size_t)(n >> 3) * RP +
                                 (l0 + m + 1) * 8 + (n & 7);
                    float itv = b2f(inh[idx]) + b2f(inl[idx]);
                    float xl = (itv - mu) * rs;
                    float nv = xl - 0.1f * acc[mt][nt][r] - 0.2f * fmaxf(xl, 0.f);
                    s += nv;
                    sq += nv * nv;
                    __hip_bfloat16 h = __float2bfloat16(nv);
                    outh[idx] = *(short*)&h;
                    outl[idx] = f2b(nv - __bfloat162float(h));
                }
        #pragma unroll
        for (int off = 32; off > 0; off >>= 1) {
            s += __shfl_down(s, off);
            sq += __shfl_down(sq, off);
        }
        __shared__ float sr[4];
        int w = tid >> 6;
        if (lane == 0) { sr[w] = s; sr[2 + w] = sq; }
        __syncthreads();
        if (tid == 0) {
            atomicAdd(&part_out[b * 2], sr[0] + sr[1]);
            atomicAdd(&part_out[b * 2 + 1], sr[2] + sr[3]);
        }
    } else {
        #pragma unroll
        for (int mt = 0; mt < 4; mt++)
            #pragma unroll
            for (int nt = 0; nt < 4; nt++)
                #pragma unroll
                for (int r = 0; r < 4; r++) {
                    int m = mt * 16 + q * 4 + r;
                    int n = co0 + nt * 16 + lane15;
                    size_t idx = obase + (size_t)(n >> 3) * RP +
                                 (l0 + m + 1) * 8 + (n & 7);
                    outh[idx] = f2b(fmaxf(acc[mt][nt][r], 0.f));
                }
    }
}

// Final 192->2 conv body from a2 [32][32oct][514][8] bf16 octet-planar.
__device__ __forceinline__ void h3_body(int bid, const short* __restrict__ a2,
                                        const float* __restrict__ w3,
                                        float* __restrict__ out, int t) {
    __shared__ float ws3[2 * 192 * 3];
    int tid = threadIdx.x;
    for (int i = tid; i < 2 * 192 * 3; i += 128) ws3[i] = w3[i];
    __syncthreads();
    int b = bid >> 3, sl = bid & 7;
    int l = sl * 64 + (tid >> 1);
    int ch = tid & 1;
    const short* ab = a2 + (size_t)b * 32 * RP;
    const float* wc = ws3 + ch * 576;
    float a = 0.f;
    #pragma unroll 4
    for (int oct = 0; oct < 24; oct++) {
        const short* p = ab + (size_t)oct * RP + l * 8;  // row l = seq l-1
        bf16x8 v0 = *(const bf16x8*)p;
        bf16x8 v1 = *(const bf16x8*)(p + 8);
        bf16x8 v2 = *(const bf16x8*)(p + 16);
        #pragma unroll
        for (int j = 0; j < 8; j++) {
            const float* wp = wc + (oct * 8 + j) * 3;
            a += wp[0] * b2f(v0[j]) + wp[1] * b2f(v1[j]) + wp[2] * b2f(v2[j]);
        }
    }
    out[(((size_t)b * ITERS + t) * 2 + ch) * LL + l] = a;
}

// F(t): op(t) || h1(t-1) || h2(t-2) || h3(t-3), one launch per pipeline step.
// All branch reads target buffers written in EARLIER launches (a1/a2
// ping-pong parities break same-launch hazards) -> no intra-launch ordering.
__global__ __launch_bounds__(128, 4) void fusedF(
    const short* __restrict__ ch, const short* __restrict__ cl,
    short* __restrict__ nh, short* __restrict__ nl,
    const short* __restrict__ wOph, const short* __restrict__ wH1,
    const short* __restrict__ wH2, const float* __restrict__ w3,
    const float* __restrict__ part_in, float* __restrict__ part_out,
    short* __restrict__ a1w, const short* __restrict__ a1r,
    short* __restrict__ a2w, const short* __restrict__ a2r,
    float* __restrict__ out, int t3, int opB, int h1B, int h2B) {
    int bid = blockIdx.x;
    if (bid < opB) {
        conv_body<13, 52, 52, 384, 1>(bid, ch, cl, wOph, part_in, part_out,
                                      nh, nl);
    } else if (bid < opB + h1B) {
        conv_body<12, 52, 48, 384, 0>(bid - opB, ch, nullptr, wH1, nullptr,
                                      nullptr, a1w, nullptr);
    } else if (bid < opB + h1B + h2B) {
        conv_body<12, 48, 32, 256, 0>(bid - opB - h1B, a1r, nullptr, wH2,
                                      nullptr, nullptr, a2w, nullptr);
    } else {
        h3_body(bid - opB - h1B - h2B, a2r, w3, out, t3);
    }
}

extern "C" void kernel_launch(void* const* d_in, const int* in_sizes, int n_in,
                              void* d_out, int out_size, void* d_ws, size_t ws_size,
                              hipStream_t stream) {
    const float* x = (const float*)d_in[0];
    const float* proj_w = (const float*)d_in[2];
    const float* op_w = (const float*)d_in[3];
    const float* h1_w = (const float*)d_in[4];
    const float* h2_w = (const float*)d_in[5];
    const float* h3_w = (const float*)d_in[6];
    float* out = (float*)d_out;

    char* base = (char*)d_ws;
    size_t off = 0;
    auto alloc = [&](size_t bytes) {
        char* p = base + off;
        off += (bytes + 255) & ~(size_t)255;
        return p;
    };
    const size_t ITB = (size_t)BB * 52 * RP * 2;  // state buffer bytes
    short* itAh = (short*)alloc(ITB);
    short* itAl = (short*)alloc(ITB);
    short* itBh = (short*)alloc(ITB);
    short* itBl = (short*)alloc(ITB);
    short* a1A = (short*)alloc((size_t)BB * 48 * RP * 2);
    short* a1B = (short*)alloc((size_t)BB * 48 * RP * 2);
    short* a2A = (short*)alloc((size_t)BB * 32 * RP * 2);
    short* a2B = (short*)alloc((size_t)BB * 32 * RP * 2);
    short* wOph = (short*)alloc((size_t)3 * 52 * 384 * 8 * 2);
    short* wH1 = (short*)alloc((size_t)3 * 48 * 384 * 8 * 2);
    short* wH2 = (short*)alloc((size_t)3 * 48 * 256 * 8 * 2);
    float* part = (float*)alloc((size_t)(ITERS + 1) * 64 * 4);
    if (off > ws_size) return;

    wsplit_op<<<(3 * 52 * 384 * 8 + 255) / 256, 256, 0, stream>>>(op_w, wOph);
    wsplit_h<<<(3 * 48 * 384 * 8 + 255) / 256, 256, 0, stream>>>(h1_w, wH1, 384, 384);
    wsplit_h<<<(3 * 48 * 256 * 8 + 255) / 256, 256, 0, stream>>>(h2_w, wH2, 256, 192);
    init_rows<<<BB * LROWS, 64, 0, stream>>>(x, itAh, itAl, itBh, itBl, a1A,
                                             a1B, a2A, a2B);
    zero_part<<<5, 256, 0, stream>>>(part, (ITERS + 1) * 64);
    proj_relu<<<BB * 8, 256, 0, stream>>>(x, proj_w, itAh, itAl, part);

    short* a1buf[2] = {a1A, a1B};
    short* a2buf[2] = {a2A, a2B};
    short *ch = itAh, *cl = itAl, *nh = itBh, *nl = itBl;
    // Pipeline steps t=0..18: op(t<=15), h1(t-1), h2(t-2), h3(t-3).
    for (int t = 0; t <= ITERS + 2; t++) {
        int opB = (t < ITERS) ? 768 : 0;
        int h1B = (t >= 1 && t <= ITERS) ? 768 : 0;
        int h2B = (t >= 2 && t <= ITERS + 1) ? 512 : 0;
        int h3B = (t >= 3) ? 256 : 0;
        int tp = (t < ITERS) ? t : 0;  // part slot (unused when opB==0)
        fusedF<<<opB + h1B + h2B + h3B, 128, 0, stream>>>(
            ch, cl, nh, nl, wOph, wH1, wH2, h3_w, part + tp * 64,
            part + (tp + 1) * 64, a1buf[(t - 1) & 1], a1buf[(t - 2) & 1],
            a2buf[(t - 2) & 1], a2buf[(t - 3) & 1], out, t - 3, opB, h1B, h2B);
        if (t < ITERS) {
            short* th = ch; ch = nh; nh = th;
            short* tl = cl; cl = nl; nl = tl;
        }
    }
}

// Round 16
// 1238.654 us; speedup vs baseline: 1.3547x; 1.2845x over previous
//
#include <hip/hip_runtime.h>
#include <hip/hip_bf16.h>

#define BB 32
#define WW 384
#define LL 512
#define ITERS 16
#define NPB (WW * LL)
#define LROWS 514            // 1 + 512 + 1 halo rows
#define RP (LROWS * 8)       // shorts per octet-plane (4112)

typedef __attribute__((ext_vector_type(8))) short bf16x8;
typedef __attribute__((ext_vector_type(4))) float f32x4;

__device__ __forceinline__ float b2f(short s) {
    unsigned u = ((unsigned)(unsigned short)s) << 16;
    float f;
    __builtin_memcpy(&f, &u, 4);
    return f;
}
__device__ __forceinline__ short f2b(float v) {
    __hip_bfloat16 h = __float2bfloat16(v);
    return *(short*)&h;
}

// ---------------------------------------------------------------- prep
// op_w [384(co)][385(ci)][3] f32 -> Wh [3][52][384][8] bf16.
// Conv runs A-hi x B-hi only (state-lo/weight-lo effects ~1e-3, threshold
// 7.9e-3). State keeps full hi/lo in MEMORY so LN/xl stays fp32-accurate.
__global__ void wsplit_op(const float* __restrict__ w, short* __restrict__ wh) {
    int i = blockIdx.x * 256 + threadIdx.x;
    if (i >= 3 * 52 * 384 * 8) return;
    int e = i & 7, co = (i >> 3) % 384, oct = (i >> 3) / 384 % 52,
        tap = i / (8 * 384 * 52);
    int ci = oct * 8 + e;
    float v = (ci < 385) ? w[(co * 385 + ci) * 3 + tap] : 0.f;
    wh[i] = f2b(v);
}

// src [CO_real][384(ci)][3] f32 -> dst [3][48][COD][8] bf16 (co>=CO_real -> 0)
__global__ void wsplit_h(const float* __restrict__ w, short* __restrict__ wh,
                         int COD, int CO_real) {
    int i = blockIdx.x * 256 + threadIdx.x;
    if (i >= 3 * 48 * COD * 8) return;
    int e = i & 7, co = (i >> 3) % COD, oct = (i >> 3) / COD % 48,
        tap = i / (8 * COD * 48);
    int ci = oct * 8 + e;
    float v = (co < CO_real) ? w[(co * 384 + ci) * 3 + tap] : 0.f;
    wh[i] = f2b(v);
}

// Zero halo rows (all buffers), install x channel (octet 48, elem 0) + zero
// pad octets 48..51 in both state ping-pong buffers.
__global__ void init_rows(const float* __restrict__ x, short* itAh, short* itAl,
                          short* itBh, short* itBl, short* a1A, short* a1B,
                          short* a2A, short* a2B) {
    int row = blockIdx.x % LROWS, b = blockIdx.x / LROWS;
    int tid = threadIdx.x;
    size_t sb = (size_t)b * 52 * RP;
    if (row == 0 || row == LROWS - 1) {
        for (int i = tid; i < 52 * 8; i += 64) {
            size_t o = sb + (size_t)(i >> 3) * RP + row * 8 + (i & 7);
            itAh[o] = 0; itAl[o] = 0; itBh[o] = 0; itBl[o] = 0;
        }
        for (int i = tid; i < 48 * 8; i += 64) {
            size_t o = (size_t)b * 48 * RP + (size_t)(i >> 3) * RP + row * 8 + (i & 7);
            a1A[o] = 0; a1B[o] = 0;
        }
        for (int i = tid; i < 32 * 8; i += 64) {
            size_t o = (size_t)b * 32 * RP + (size_t)(i >> 3) * RP + row * 8 + (i & 7);
            a2A[o] = 0; a2B[o] = 0;
        }
    } else if (tid < 32) {
        int oct = 48 + (tid >> 3), e = tid & 7;
        short h = 0, l = 0;
        if (oct == 48 && e == 0) {
            float xv = x[b * LL + row - 1];
            __hip_bfloat16 xh = __float2bfloat16(xv);
            h = *(short*)&xh;
            l = f2b(xv - __bfloat162float(xh));
        }
        size_t o = sb + (size_t)oct * RP + row * 8 + e;
        itAh[o] = h; itAl[o] = l; itBh[o] = h; itBl[o] = l;
    }
}

__global__ void zero_part(float* part, int n) {
    int i = blockIdx.x * 256 + threadIdx.x;
    if (i < n) part[i] = 0.f;
}

// it0 = relu(conv1d(x, proj_w)) -> octet-planar hi/lo + LN stats.
__global__ __launch_bounds__(256) void proj_relu(const float* __restrict__ x,
                                                 const float* __restrict__ wp,
                                                 short* __restrict__ oh,
                                                 short* __restrict__ ol,
                                                 float* __restrict__ part) {
    int b = blockIdx.x >> 3, sl = blockIdx.x & 7;
    int tid = threadIdx.x;
    __shared__ float ws[WW * 3];
    __shared__ float xs[66];
    for (int i = tid; i < WW * 3; i += 256) ws[i] = wp[i];
    int l0 = sl * 64;
    for (int i = tid; i < 66; i += 256) {
        int l = l0 + i - 1;
        xs[i] = (l >= 0 && l < LL) ? x[b * LL + l] : 0.f;
    }
    __syncthreads();
    size_t sb = (size_t)b * 52 * RP;
    float s = 0.f, sq = 0.f;
    for (int idx = tid; idx < 64 * WW; idx += 256) {
        int lo = idx / WW, co = idx % WW;
        float v = fmaxf(ws[co * 3] * xs[lo] + ws[co * 3 + 1] * xs[lo + 1] +
                            ws[co * 3 + 2] * xs[lo + 2], 0.f);
        size_t o = sb + (size_t)(co >> 3) * RP + (l0 + lo + 1) * 8 + (co & 7);
        __hip_bfloat16 h = __float2bfloat16(v);
        oh[o] = *(short*)&h;
        ol[o] = f2b(v - __bfloat162float(h));
        s += v; sq += v * v;
    }
    #pragma unroll
    for (int off = 32; off > 0; off >>= 1) {
        s += __shfl_down(s, off);
        sq += __shfl_down(sq, off);
    }
    __shared__ float sr[8];
    int w = tid >> 6;
    if ((tid & 63) == 0) { sr[w] = s; sr[4 + w] = sq; }
    __syncthreads();
    if (tid == 0) {
        atomicAdd(&part[b * 2], sr[0] + sr[1] + sr[2] + sr[3]);
        atomicAdd(&part[b * 2 + 1], sr[4] + sr[5] + sr[6] + sr[7]);
    }
}

// ------------------------------------------------- MFMA implicit-GEMM conv
// Direct-global octet-planar loads, no LDS staging, no K-loop barriers.
// 3-deep SOFTWARE PIPELINE; frags are named scalars via macros (arrays/
// lambdas defeat SROA -> scratch spills, r7/r8). 3-branch kernel keeps
// VGPR <= 128 (r12: 112 -> 4 waves/SIMD; adding the h3 branch pushed it to
// 148 -> 3 waves/SIMD, a 1.72x per-MFMA throughput loss measured r12 vs
// r13; forcing the cap via launch_bounds spills — r15). h3 runs as its own
// tiny kernel instead.
// Block: 2 waves splitting co; wave tile 64l x 64co (4x4 16x16x32 MFMA).
// bid layout: g=bid&255 (b*8+lt), ct=bid>>8 -> A-sharers on same XCD.
// MODE 0: relu -> bf16 octet-planar out. MODE 1: energy epilogue + LN stats.

#define DECL_SET(S) \
    bf16x8 ah0##S, ah1##S, ah2##S, ah3##S, bh0##S, bh1##S, bh2##S, bh3##S;

#define LOAD_SET(S)                                                        \
    do {                                                                   \
        size_t ao_ = arow + (size_t)kc * (4 * RP) + tap * 8;               \
        size_t bo_ = brow + (size_t)(tap * CHUNKS + kc) * (4 * COD * 8);   \
        ah0##S = *(const bf16x8*)(inh + ao_);                              \
        ah1##S = *(const bf16x8*)(inh + ao_ + 16 * 8);                     \
        ah2##S = *(const bf16x8*)(inh + ao_ + 32 * 8);                     \
        ah3##S = *(const bf16x8*)(inh + ao_ + 48 * 8);                     \
        bh0##S = *(const bf16x8*)(wh + bo_);                               \
        bh1##S = *(const bf16x8*)(wh + bo_ + 16 * 8);                      \
        bh2##S = *(const bf16x8*)(wh + bo_ + 32 * 8);                      \
        bh3##S = *(const bf16x8*)(wh + bo_ + 48 * 8);                      \
        tap++;                                                             \
        if (tap == 3) { tap = 0; kc++; }                                   \
    } while (0)

#define MM(S, MT, NT)                                                      \
    acc[MT][NT] = __builtin_amdgcn_mfma_f32_16x16x32_bf16(                 \
        ah##MT##S, bh##NT##S, acc[MT][NT], 0, 0, 0);

#define MFMA_SET(S)                                                        \
    do {                                                                   \
        MM(S, 0, 0) MM(S, 0, 1) MM(S, 0, 2) MM(S, 0, 3)                    \
        MM(S, 1, 0) MM(S, 1, 1) MM(S, 1, 2) MM(S, 1, 3)                    \
        MM(S, 2, 0) MM(S, 2, 1) MM(S, 2, 2) MM(S, 2, 3)                    \
        MM(S, 3, 0) MM(S, 3, 1) MM(S, 3, 2) MM(S, 3, 3)                    \
    } while (0)

template <int CHUNKS, int IOCT, int OOCT, int COD, int MODE>
__device__ __forceinline__ void conv_body(
    int bid, const short* __restrict__ inh, const short* __restrict__ inl,
    const short* __restrict__ wh, const float* __restrict__ part_in,
    float* __restrict__ part_out, short* __restrict__ outh,
    short* __restrict__ outl) {
    int g = bid & 255;
    int ct = bid >> 8;
    int b = g >> 3, lt = g & 7;
    int l0 = lt * 64;
    int tid = threadIdx.x;
    int lane = tid & 63;
    int wn = __builtin_amdgcn_readfirstlane(tid >> 6);
    int lane15 = lane & 15, q = lane >> 4;
    int co0 = ct * 128 + wn * 64;
    const size_t ibase = (size_t)b * IOCT * RP;

    f32x4 acc[4][4];
    #pragma unroll
    for (int i = 0; i < 4; i++)
        #pragma unroll
        for (int j = 0; j < 4; j++) acc[i][j] = (f32x4){0.f, 0.f, 0.f, 0.f};

    const size_t arow = ibase + (size_t)q * RP + (l0 + lane15) * 8;
    const size_t brow = ((size_t)q * COD + co0 + lane15) * 8;

    constexpr int NIT = CHUNKS * 3;  // 39 or 36 — both divisible by 3
    static_assert(NIT % 3 == 0, "driver assumes NIT % 3 == 0");
    int kc = 0, tap = 0;

    DECL_SET(A)
    DECL_SET(B)
    DECL_SET(C)
    LOAD_SET(A);
    LOAD_SET(B);
    int it = 0;
    #pragma unroll 1
    for (; it + 5 < NIT; it += 3) {
        LOAD_SET(C);
        MFMA_SET(A);
        LOAD_SET(A);
        MFMA_SET(B);
        LOAD_SET(B);
        MFMA_SET(C);
    }
    LOAD_SET(C);
    MFMA_SET(A);
    MFMA_SET(B);
    MFMA_SET(C);

    const size_t obase = (size_t)b * OOCT * RP;
    if (MODE == 1) {
        float s_in = part_in[b * 2], sq_in = part_in[b * 2 + 1];
        float mu = s_in / (float)NPB;
        float var = sq_in / (float)NPB - mu * mu;
        float rs = rsqrtf(var + 1e-5f);
        float s = 0.f, sq = 0.f;
        #pragma unroll
        for (int mt = 0; mt < 4; mt++)
            #pragma unroll
            for (int nt = 0; nt < 4; nt++)
                #pragma unroll
                for (int r = 0; r < 4; r++) {
                    int m = mt * 16 + q * 4 + r;
                    int n = co0 + nt * 16 + lane15;
                    size_t idx = ibase + (size_t)(n >> 3) * RP +
                                 (l0 + m + 1) * 8 + (n & 7);
                    float itv = b2f(inh[idx]) + b2f(inl[idx]);
                    float xl = (itv - mu) * rs;
                    float nv = xl - 0.1f * acc[mt][nt][r] - 0.2f * fmaxf(xl, 0.f);
                    s += nv;
                    sq += nv * nv;
                    __hip_bfloat16 h = __float2bfloat16(nv);
                    outh[idx] = *(short*)&h;
                    outl[idx] = f2b(nv - __bfloat162float(h));
                }
        #pragma unroll
        for (int off = 32; off > 0; off >>= 1) {
            s += __shfl_down(s, off);
            sq += __shfl_down(sq, off);
        }
        __shared__ float sr[4];
        int w = tid >> 6;
        if (lane == 0) { sr[w] = s; sr[2 + w] = sq; }
        __syncthreads();
        if (tid == 0) {
            atomicAdd(&part_out[b * 2], sr[0] + sr[1]);
            atomicAdd(&part_out[b * 2 + 1], sr[2] + sr[3]);
        }
    } else {
        #pragma unroll
        for (int mt = 0; mt < 4; mt++)
            #pragma unroll
            for (int nt = 0; nt < 4; nt++)
                #pragma unroll
                for (int r = 0; r < 4; r++) {
                    int m = mt * 16 + q * 4 + r;
                    int n = co0 + nt * 16 + lane15;
                    size_t idx = obase + (size_t)(n >> 3) * RP +
                                 (l0 + m + 1) * 8 + (n & 7);
                    outh[idx] = f2b(fmaxf(acc[mt][nt][r], 0.f));
                }
    }
}

// Final 192->2 conv from a2 [32][32oct][514][8] bf16 octet-planar.
__global__ __launch_bounds__(128) void h3k(const short* __restrict__ a2,
                                           const float* __restrict__ w3,
                                           float* __restrict__ out, int t) {
    __shared__ float ws3[2 * 192 * 3];
    int tid = threadIdx.x;
    for (int i = tid; i < 2 * 192 * 3; i += 128) ws3[i] = w3[i];
    __syncthreads();
    int b = blockIdx.x >> 3, sl = blockIdx.x & 7;
    int l = sl * 64 + (tid >> 1);
    int ch = tid & 1;
    const short* ab = a2 + (size_t)b * 32 * RP;
    const float* wc = ws3 + ch * 576;
    float a = 0.f;
    #pragma unroll 4
    for (int oct = 0; oct < 24; oct++) {
        const short* p = ab + (size_t)oct * RP + l * 8;  // row l = seq l-1
        bf16x8 v0 = *(const bf16x8*)p;
        bf16x8 v1 = *(const bf16x8*)(p + 8);
        bf16x8 v2 = *(const bf16x8*)(p + 16);
        #pragma unroll
        for (int j = 0; j < 8; j++) {
            const float* wp = wc + (oct * 8 + j) * 3;
            a += wp[0] * b2f(v0[j]) + wp[1] * b2f(v1[j]) + wp[2] * b2f(v2[j]);
        }
    }
    out[(((size_t)b * ITERS + t) * 2 + ch) * LL + l] = a;
}

// F(t): op(t) [0..opB) || h1(t-1) [opB..opB+h1B) || h2(t-2) [rest].
// All branch reads target buffers written in EARLIER launches (a1/a2
// ping-pong parities break same-launch hazards) -> no intra-launch ordering.
__global__ __launch_bounds__(128) void fusedF(
    const short* __restrict__ ch, const short* __restrict__ cl,
    short* __restrict__ nh, short* __restrict__ nl,
    const short* __restrict__ wOph, const short* __restrict__ wH1,
    const short* __restrict__ wH2, const float* __restrict__ part_in,
    float* __restrict__ part_out, short* __restrict__ a1w,
    const short* __restrict__ a1r, short* __restrict__ a2w,
    int opB, int h1B) {
    int bid = blockIdx.x;
    if (bid < opB) {
        conv_body<13, 52, 52, 384, 1>(bid, ch, cl, wOph, part_in, part_out,
                                      nh, nl);
    } else if (bid < opB + h1B) {
        conv_body<12, 52, 48, 384, 0>(bid - opB, ch, nullptr, wH1, nullptr,
                                      nullptr, a1w, nullptr);
    } else {
        conv_body<12, 48, 32, 256, 0>(bid - opB - h1B, a1r, nullptr, wH2,
                                      nullptr, nullptr, a2w, nullptr);
    }
}

extern "C" void kernel_launch(void* const* d_in, const int* in_sizes, int n_in,
                              void* d_out, int out_size, void* d_ws, size_t ws_size,
                              hipStream_t stream) {
    const float* x = (const float*)d_in[0];
    const float* proj_w = (const float*)d_in[2];
    const float* op_w = (const float*)d_in[3];
    const float* h1_w = (const float*)d_in[4];
    const float* h2_w = (const float*)d_in[5];
    const float* h3_w = (const float*)d_in[6];
    float* out = (float*)d_out;

    char* base = (char*)d_ws;
    size_t off = 0;
    auto alloc = [&](size_t bytes) {
        char* p = base + off;
        off += (bytes + 255) & ~(size_t)255;
        return p;
    };
    const size_t ITB = (size_t)BB * 52 * RP * 2;  // state buffer bytes
    short* itAh = (short*)alloc(ITB);
    short* itAl = (short*)alloc(ITB);
    short* itBh = (short*)alloc(ITB);
    short* itBl = (short*)alloc(ITB);
    short* a1A = (short*)alloc((size_t)BB * 48 * RP * 2);
    short* a1B = (short*)alloc((size_t)BB * 48 * RP * 2);
    short* a2A = (short*)alloc((size_t)BB * 32 * RP * 2);
    short* a2B = (short*)alloc((size_t)BB * 32 * RP * 2);
    short* wOph = (short*)alloc((size_t)3 * 52 * 384 * 8 * 2);
    short* wH1 = (short*)alloc((size_t)3 * 48 * 384 * 8 * 2);
    short* wH2 = (short*)alloc((size_t)3 * 48 * 256 * 8 * 2);
    float* part = (float*)alloc((size_t)(ITERS + 1) * 64 * 4);
    if (off > ws_size) return;

    wsplit_op<<<(3 * 52 * 384 * 8 + 255) / 256, 256, 0, stream>>>(op_w, wOph);
    wsplit_h<<<(3 * 48 * 384 * 8 + 255) / 256, 256, 0, stream>>>(h1_w, wH1, 384, 384);
    wsplit_h<<<(3 * 48 * 256 * 8 + 255) / 256, 256, 0, stream>>>(h2_w, wH2, 256, 192);
    init_rows<<<BB * LROWS, 64, 0, stream>>>(x, itAh, itAl, itBh, itBl, a1A,
                                             a1B, a2A, a2B);
    zero_part<<<5, 256, 0, stream>>>(part, (ITERS + 1) * 64);
    proj_relu<<<BB * 8, 256, 0, stream>>>(x, proj_w, itAh, itAl, part);

    short* a1buf[2] = {a1A, a1B};
    short* a2buf[2] = {a2A, a2B};
    short *ch = itAh, *cl = itAl, *nh = itBh, *nl = itBl;
    // Pipeline steps t=0..17: op(t<=15), h1(t-1), h2(t-2) in F; h3(t-3) solo.
    for (int t = 0; t < ITERS + 2; t++) {
        int opB = (t < ITERS) ? 768 : 0;
        int h1B = (t >= 1 && t <= ITERS) ? 768 : 0;
        int h2B = (t >= 2 && t <= ITERS + 1) ? 512 : 0;
        int tp = (t < ITERS) ? t : 0;  // part slot (unused when opB==0)
        fusedF<<<opB + h1B + h2B, 128, 0, stream>>>(
            ch, cl, nh, nl, wOph, wH1, wH2, part + tp * 64,
            part + (tp + 1) * 64, a1buf[(t - 1) & 1], a1buf[(t - 2) & 1],
            a2buf[(t - 2) & 1], opB, h1B);
        if (t >= 3)
            h3k<<<256, 128, 0, stream>>>(a2buf[(t - 3) & 1], h3_w, out, t - 3);
        if (t < ITERS) {
            short* th = ch; ch = nh; nh = th;
            short* tl = cl; cl = nl; nl = tl;
        }
    }
    // Remaining: h3(ITERS-1) (a2 parity (ITERS-1)&1 written at t=ITERS+1).
    h3k<<<256, 128, 0, stream>>>(a2buf[(ITERS - 1) & 1], h3_w, out, ITERS - 1);
}

// Round 17
// 1210.193 us; speedup vs baseline: 1.3866x; 1.0235x over previous
//
#include <hip/hip_runtime.h>
#include <hip/hip_bf16.h>

#define BB 32
#define WW 384
#define LL 512
#define ITERS 16
#define NPB (WW * LL)
#define LROWS 514            // 1 + 512 + 1 halo rows
#define RP (LROWS * 8)       // shorts per octet-plane (4112)

typedef __attribute__((ext_vector_type(8))) short bf16x8;
typedef __attribute__((ext_vector_type(4))) float f32x4;

__device__ __forceinline__ float b2f(short s) {
    unsigned u = ((unsigned)(unsigned short)s) << 16;
    float f;
    __builtin_memcpy(&f, &u, 4);
    return f;
}
__device__ __forceinline__ short f2b(float v) {
    __hip_bfloat16 h = __float2bfloat16(v);
    return *(short*)&h;
}

// ---------------------------------------------------------------- prep
// op_w [384(co)][385(ci)][3] f32 -> Wh [3][48][384][8] bf16 (ci<384 only;
// the x channel ci=384 is folded into the op epilogue in fp32 via wx).
// Conv runs A-hi x B-hi only (state-lo/weight-lo effects ~1e-3, threshold
// 7.9e-3). State keeps full hi/lo in MEMORY so LN/xl stays fp32-accurate.
__global__ void wsplit_op(const float* __restrict__ w, short* __restrict__ wh) {
    int i = blockIdx.x * 256 + threadIdx.x;
    if (i >= 3 * 48 * 384 * 8) return;
    int e = i & 7, co = (i >> 3) % 384, oct = (i >> 3) / 384 % 48,
        tap = i / (8 * 384 * 48);
    int ci = oct * 8 + e;
    wh[i] = f2b(w[(co * 385 + ci) * 3 + tap]);
}

// wx[tap][co] = op_w[co][384][tap] (fp32, x-channel weights)
__global__ void wx_prep(const float* __restrict__ w, float* __restrict__ wx) {
    int i = blockIdx.x * 256 + threadIdx.x;
    if (i >= 3 * 384) return;
    int co = i % 384, tap = i / 384;
    wx[tap * 384 + co] = w[(co * 385 + 384) * 3 + tap];
}

// src [CO_real][384(ci)][3] f32 -> dst [3][48][COD][8] bf16
__global__ void wsplit_h(const float* __restrict__ w, short* __restrict__ wh,
                         int COD, int CO_real) {
    int i = blockIdx.x * 256 + threadIdx.x;
    if (i >= 3 * 48 * COD * 8) return;
    int e = i & 7, co = (i >> 3) % COD, oct = (i >> 3) / COD % 48,
        tap = i / (8 * COD * 48);
    int ci = oct * 8 + e;
    float v = (co < CO_real) ? w[(co * 384 + ci) * 3 + tap] : 0.f;
    wh[i] = f2b(v);
}

// Zero halo rows of all buffers (state 48 oct, a1 48 oct, a2 24 oct).
__global__ void init_rows(short* itAh, short* itAl, short* itBh, short* itBl,
                          short* a1A, short* a1B, short* a2A, short* a2B) {
    int row = (blockIdx.x & 1) ? (LROWS - 1) : 0;
    int b = blockIdx.x >> 1;
    int tid = threadIdx.x;
    for (int i = tid; i < 48 * 8; i += 64) {
        size_t o = (size_t)b * 48 * RP + (size_t)(i >> 3) * RP + row * 8 + (i & 7);
        itAh[o] = 0; itAl[o] = 0; itBh[o] = 0; itBl[o] = 0;
        a1A[o] = 0; a1B[o] = 0;
    }
    for (int i = tid; i < 24 * 8; i += 64) {
        size_t o = (size_t)b * 24 * RP + (size_t)(i >> 3) * RP + row * 8 + (i & 7);
        a2A[o] = 0; a2B[o] = 0;
    }
}

__global__ void zero_part(float* part, int n) {
    int i = blockIdx.x * 256 + threadIdx.x;
    if (i < n) part[i] = 0.f;
}

// it0 = relu(conv1d(x, proj_w)) -> octet-planar hi/lo (48 oct) + LN stats.
__global__ __launch_bounds__(256) void proj_relu(const float* __restrict__ x,
                                                 const float* __restrict__ wp,
                                                 short* __restrict__ oh,
                                                 short* __restrict__ ol,
                                                 float* __restrict__ part) {
    int b = blockIdx.x >> 3, sl = blockIdx.x & 7;
    int tid = threadIdx.x;
    __shared__ float ws[WW * 3];
    __shared__ float xs[66];
    for (int i = tid; i < WW * 3; i += 256) ws[i] = wp[i];
    int l0 = sl * 64;
    for (int i = tid; i < 66; i += 256) {
        int l = l0 + i - 1;
        xs[i] = (l >= 0 && l < LL) ? x[b * LL + l] : 0.f;
    }
    __syncthreads();
    size_t sb = (size_t)b * 48 * RP;
    float s = 0.f, sq = 0.f;
    for (int idx = tid; idx < 64 * WW; idx += 256) {
        int lo = idx / WW, co = idx % WW;
        float v = fmaxf(ws[co * 3] * xs[lo] + ws[co * 3 + 1] * xs[lo + 1] +
                            ws[co * 3 + 2] * xs[lo + 2], 0.f);
        size_t o = sb + (size_t)(co >> 3) * RP + (l0 + lo + 1) * 8 + (co & 7);
        __hip_bfloat16 h = __float2bfloat16(v);
        oh[o] = *(short*)&h;
        ol[o] = f2b(v - __bfloat162float(h));
        s += v; sq += v * v;
    }
    #pragma unroll
    for (int off = 32; off > 0; off >>= 1) {
        s += __shfl_down(s, off);
        sq += __shfl_down(sq, off);
    }
    __shared__ float sr[8];
    int w = tid >> 6;
    if ((tid & 63) == 0) { sr[w] = s; sr[4 + w] = sq; }
    __syncthreads();
    if (tid == 0) {
        atomicAdd(&part[b * 2], sr[0] + sr[1] + sr[2] + sr[3]);
        atomicAdd(&part[b * 2 + 1], sr[4] + sr[5] + sr[6] + sr[7]);
    }
}

// ------------------------------------------------- MFMA implicit-GEMM conv
// Direct-global octet-planar loads, no LDS staging, no K-loop barriers.
// 3-deep SOFTWARE PIPELINE; frags are named scalars via macros (arrays/
// lambdas defeat SROA -> scratch spills, r7/r8). 3-branch kernel keeps
// VGPR <= 128 (r16: 120 -> 4 waves/SIMD; the 4th branch cost 28 regs ->
// 3 waves/SIMD, 1.72x per-MFMA loss r12-vs-r13; forcing cap spills, r15).
// LSPLIT=0: 2 waves split co (64l x 128co block); bid: g=bid&255, ct=bid>>8.
// LSPLIT=1: 2 waves split l (128l x 64co block, COD exact); g=bid&127.
// All branches NIT=36 (x channel folded into op epilogue in fp32).
// MODE 0: relu -> bf16 octet-planar out. MODE 1: energy epilogue + LN stats.

#define DECL_SET(S) \
    bf16x8 ah0##S, ah1##S, ah2##S, ah3##S, bh0##S, bh1##S, bh2##S, bh3##S;

#define LOAD_SET(S)                                                        \
    do {                                                                   \
        size_t ao_ = arow + (size_t)kc * (4 * RP) + tap * 8;               \
        size_t bo_ = brow + (size_t)(tap * CHUNKS + kc) * (4 * COD * 8);   \
        ah0##S = *(const bf16x8*)(inh + ao_);                              \
        ah1##S = *(const bf16x8*)(inh + ao_ + 16 * 8);                     \
        ah2##S = *(const bf16x8*)(inh + ao_ + 32 * 8);                     \
        ah3##S = *(const bf16x8*)(inh + ao_ + 48 * 8);                     \
        bh0##S = *(const bf16x8*)(wh + bo_);                               \
        bh1##S = *(const bf16x8*)(wh + bo_ + 16 * 8);                      \
        bh2##S = *(const bf16x8*)(wh + bo_ + 32 * 8);                      \
        bh3##S = *(const bf16x8*)(wh + bo_ + 48 * 8);                      \
        tap++;                                                             \
        if (tap == 3) { tap = 0; kc++; }                                   \
    } while (0)

#define MM(S, MT, NT)                                                      \
    acc[MT][NT] = __builtin_amdgcn_mfma_f32_16x16x32_bf16(                 \
        ah##MT##S, bh##NT##S, acc[MT][NT], 0, 0, 0);

#define MFMA_SET(S)                                                        \
    do {                                                                   \
        MM(S, 0, 0) MM(S, 0, 1) MM(S, 0, 2) MM(S, 0, 3)                    \
        MM(S, 1, 0) MM(S, 1, 1) MM(S, 1, 2) MM(S, 1, 3)                    \
        MM(S, 2, 0) MM(S, 2, 1) MM(S, 2, 2) MM(S, 2, 3)                    \
        MM(S, 3, 0) MM(S, 3, 1) MM(S, 3, 2) MM(S, 3, 3)                    \
    } while (0)

template <int CHUNKS, int IOCT, int OOCT, int COD, int MODE, int LSPLIT>
__device__ __forceinline__ void conv_body(
    int bid, const short* __restrict__ inh, const short* __restrict__ inl,
    const short* __restrict__ wh, const float* __restrict__ xf,
    const float* __restrict__ wx, const float* __restrict__ part_in,
    float* __restrict__ part_out, short* __restrict__ outh,
    short* __restrict__ outl) {
    int tid = threadIdx.x;
    int lane = tid & 63;
    int wn = __builtin_amdgcn_readfirstlane(tid >> 6);
    int lane15 = lane & 15, q = lane >> 4;
    int b, l0, co0;
    if (LSPLIT) {
        int g = bid & 127, ct = bid >> 7;
        b = g >> 2;
        l0 = (g & 3) * 128 + wn * 64;
        co0 = ct * 64;
    } else {
        int g = bid & 255, ct = bid >> 8;
        b = g >> 3;
        l0 = (g & 7) * 64;
        co0 = ct * 128 + wn * 64;
    }
    const size_t ibase = (size_t)b * IOCT * RP;

    f32x4 acc[4][4];
    #pragma unroll
    for (int i = 0; i < 4; i++)
        #pragma unroll
        for (int j = 0; j < 4; j++) acc[i][j] = (f32x4){0.f, 0.f, 0.f, 0.f};

    const size_t arow = ibase + (size_t)q * RP + (l0 + lane15) * 8;
    const size_t brow = ((size_t)q * COD + co0 + lane15) * 8;

    constexpr int NIT = CHUNKS * 3;  // 36 for all branches
    static_assert(NIT % 3 == 0, "driver assumes NIT % 3 == 0");
    int kc = 0, tap = 0;

    DECL_SET(A)
    DECL_SET(B)
    DECL_SET(C)
    LOAD_SET(A);
    LOAD_SET(B);
    int it = 0;
    #pragma unroll 1
    for (; it + 5 < NIT; it += 3) {
        LOAD_SET(C);
        MFMA_SET(A);
        LOAD_SET(A);
        MFMA_SET(B);
        LOAD_SET(B);
        MFMA_SET(C);
    }
    LOAD_SET(C);
    MFMA_SET(A);
    MFMA_SET(B);
    MFMA_SET(C);

    const size_t obase = (size_t)b * OOCT * RP;
    if (MODE == 1) {
        float s_in = part_in[b * 2], sq_in = part_in[b * 2 + 1];
        float mu = s_in / (float)NPB;
        float var = sq_in / (float)NPB - mu * mu;
        float rs = rsqrtf(var + 1e-5f);
        const float* xb = xf + b * LL;
        float s = 0.f, sq = 0.f;
        #pragma unroll
        for (int nt = 0; nt < 4; nt++) {
            int n = co0 + nt * 16 + lane15;
            float w0 = wx[n], w1 = wx[384 + n], w2 = wx[768 + n];
            #pragma unroll
            for (int mt = 0; mt < 4; mt++)
                #pragma unroll
                for (int r = 0; r < 4; r++) {
                    int m = mt * 16 + q * 4 + r;
                    int l = l0 + m;
                    size_t idx = ibase + (size_t)(n >> 3) * RP +
                                 (l + 1) * 8 + (n & 7);
                    // x-channel contribution (fp32-exact)
                    float xm1 = (l > 0) ? xb[l - 1] : 0.f;
                    float xp1 = (l < LL - 1) ? xb[l + 1] : 0.f;
                    float c = acc[mt][nt][r] + w0 * xm1 + w1 * xb[l] + w2 * xp1;
                    float itv = b2f(inh[idx]) + b2f(inl[idx]);
                    float xl = (itv - mu) * rs;
                    float nv = xl - 0.1f * c - 0.2f * fmaxf(xl, 0.f);
                    s += nv;
                    sq += nv * nv;
                    __hip_bfloat16 h = __float2bfloat16(nv);
                    outh[idx] = *(short*)&h;
                    outl[idx] = f2b(nv - __bfloat162float(h));
                }
        }
        #pragma unroll
        for (int off = 32; off > 0; off >>= 1) {
            s += __shfl_down(s, off);
            sq += __shfl_down(sq, off);
        }
        __shared__ float sr[4];
        int w = tid >> 6;
        if (lane == 0) { sr[w] = s; sr[2 + w] = sq; }
        __syncthreads();
        if (tid == 0) {
            atomicAdd(&part_out[b * 2], sr[0] + sr[1]);
            atomicAdd(&part_out[b * 2 + 1], sr[2] + sr[3]);
        }
    } else {
        #pragma unroll
        for (int mt = 0; mt < 4; mt++)
            #pragma unroll
            for (int nt = 0; nt < 4; nt++)
                #pragma unroll
                for (int r = 0; r < 4; r++) {
                    int m = mt * 16 + q * 4 + r;
                    int n = co0 + nt * 16 + lane15;
                    size_t idx = obase + (size_t)(n >> 3) * RP +
                                 (l0 + m + 1) * 8 + (n & 7);
                    outh[idx] = f2b(fmaxf(acc[mt][nt][r], 0.f));
                }
    }
}

// Final 192->2 conv from a2 [32][24oct][514][8] bf16 octet-planar.
__global__ __launch_bounds__(128) void h3k(const short* __restrict__ a2,
                                           const float* __restrict__ w3,
                                           float* __restrict__ out, int t) {
    __shared__ float ws3[2 * 192 * 3];
    int tid = threadIdx.x;
    for (int i = tid; i < 2 * 192 * 3; i += 128) ws3[i] = w3[i];
    __syncthreads();
    int b = blockIdx.x >> 3, sl = blockIdx.x & 7;
    int l = sl * 64 + (tid >> 1);
    int ch = tid & 1;
    const short* ab = a2 + (size_t)b * 24 * RP;
    const float* wc = ws3 + ch * 576;
    float a = 0.f;
    #pragma unroll 4
    for (int oct = 0; oct < 24; oct++) {
        const short* p = ab + (size_t)oct * RP + l * 8;  // row l = seq l-1
        bf16x8 v0 = *(const bf16x8*)p;
        bf16x8 v1 = *(const bf16x8*)(p + 8);
        bf16x8 v2 = *(const bf16x8*)(p + 16);
        #pragma unroll
        for (int j = 0; j < 8; j++) {
            const float* wp = wc + (oct * 8 + j) * 3;
            a += wp[0] * b2f(v0[j]) + wp[1] * b2f(v1[j]) + wp[2] * b2f(v2[j]);
        }
    }
    out[(((size_t)b * ITERS + t) * 2 + ch) * LL + l] = a;
}

// F(t): op(t) [0..opB) || h1(t-1) [opB..opB+h1B) || h2(t-2) [rest].
// All branch reads target buffers written in EARLIER launches (a1/a2
// ping-pong parities break same-launch hazards) -> no intra-launch ordering.
__global__ __launch_bounds__(128) void fusedF(
    const short* __restrict__ ch, const short* __restrict__ cl,
    short* __restrict__ nh, short* __restrict__ nl,
    const short* __restrict__ wOph, const short* __restrict__ wH1,
    const short* __restrict__ wH2, const float* __restrict__ xf,
    const float* __restrict__ wx, const float* __restrict__ part_in,
    float* __restrict__ part_out, short* __restrict__ a1w,
    const short* __restrict__ a1r, short* __restrict__ a2w,
    int opB, int h1B) {
    int bid = blockIdx.x;
    if (bid < opB) {
        conv_body<12, 48, 48, 384, 1, 0>(bid, ch, cl, wOph, xf, wx, part_in,
                                         part_out, nh, nl);
    } else if (bid < opB + h1B) {
        conv_body<12, 48, 48, 384, 0, 0>(bid - opB, ch, nullptr, wH1, nullptr,
                                         nullptr, nullptr, nullptr, a1w,
                                         nullptr);
    } else {
        conv_body<12, 48, 24, 192, 0, 1>(bid - opB - h1B, a1r, nullptr, wH2,
                                         nullptr, nullptr, nullptr, nullptr,
                                         a2w, nullptr);
    }
}

extern "C" void kernel_launch(void* const* d_in, const int* in_sizes, int n_in,
                              void* d_out, int out_size, void* d_ws, size_t ws_size,
                              hipStream_t stream) {
    const float* x = (const float*)d_in[0];
    const float* proj_w = (const float*)d_in[2];
    const float* op_w = (const float*)d_in[3];
    const float* h1_w = (const float*)d_in[4];
    const float* h2_w = (const float*)d_in[5];
    const float* h3_w = (const float*)d_in[6];
    float* out = (float*)d_out;

    char* base = (char*)d_ws;
    size_t off = 0;
    auto alloc = [&](size_t bytes) {
        char* p = base + off;
        off += (bytes + 255) & ~(size_t)255;
        return p;
    };
    const size_t ITB = (size_t)BB * 48 * RP * 2;  // state buffer bytes
    short* itAh = (short*)alloc(ITB);
    short* itAl = (short*)alloc(ITB);
    short* itBh = (short*)alloc(ITB);
    short* itBl = (short*)alloc(ITB);
    short* a1A = (short*)alloc((size_t)BB * 48 * RP * 2);
    short* a1B = (short*)alloc((size_t)BB * 48 * RP * 2);
    short* a2A = (short*)alloc((size_t)BB * 24 * RP * 2);
    short* a2B = (short*)alloc((size_t)BB * 24 * RP * 2);
    short* wOph = (short*)alloc((size_t)3 * 48 * 384 * 8 * 2);
    short* wH1 = (short*)alloc((size_t)3 * 48 * 384 * 8 * 2);
    short* wH2 = (short*)alloc((size_t)3 * 48 * 192 * 8 * 2);
    float* wx = (float*)alloc((size_t)3 * 384 * 4);
    float* part = (float*)alloc((size_t)(ITERS + 1) * 64 * 4);
    if (off > ws_size) return;

    wsplit_op<<<(3 * 48 * 384 * 8 + 255) / 256, 256, 0, stream>>>(op_w, wOph);
    wx_prep<<<5, 256, 0, stream>>>(op_w, wx);
    wsplit_h<<<(3 * 48 * 384 * 8 + 255) / 256, 256, 0, stream>>>(h1_w, wH1, 384, 384);
    wsplit_h<<<(3 * 48 * 192 * 8 + 255) / 256, 256, 0, stream>>>(h2_w, wH2, 192, 192);
    init_rows<<<BB * 2, 64, 0, stream>>>(itAh, itAl, itBh, itBl, a1A, a1B,
                                         a2A, a2B);
    zero_part<<<5, 256, 0, stream>>>(part, (ITERS + 1) * 64);
    proj_relu<<<BB * 8, 256, 0, stream>>>(x, proj_w, itAh, itAl, part);

    short* a1buf[2] = {a1A, a1B};
    short* a2buf[2] = {a2A, a2B};
    short *ch = itAh, *cl = itAl, *nh = itBh, *nl = itBl;
    // Pipeline steps t=0..17: op(t<=15), h1(t-1), h2(t-2) in F; h3(t-3) solo.
    for (int t = 0; t < ITERS + 2; t++) {
        int opB = (t < ITERS) ? 768 : 0;
        int h1B = (t >= 1 && t <= ITERS) ? 768 : 0;
        int h2B = (t >= 2 && t <= ITERS + 1) ? 384 : 0;
        int tp = (t < ITERS) ? t : 0;  // part slot (unused when opB==0)
        fusedF<<<opB + h1B + h2B, 128, 0, stream>>>(
            ch, cl, nh, nl, wOph, wH1, wH2, x, wx, part + tp * 64,
            part + (tp + 1) * 64, a1buf[(t - 1) & 1], a1buf[(t - 2) & 1],
            a2buf[(t - 2) & 1], opB, h1B);
        if (t >= 3)
            h3k<<<256, 128, 0, stream>>>(a2buf[(t - 3) & 1], h3_w, out, t - 3);
        if (t < ITERS) {
            short* th = ch; ch = nh; nh = th;
            short* tl = cl; cl = nl; nl = tl;
        }
    }
    // Remaining: h3(ITERS-1) (a2 parity (ITERS-1)&1 written at t=ITERS+1).
    h3k<<<256, 128, 0, stream>>>(a2buf[(ITERS - 1) & 1], h3_w, out, ITERS - 1);
}